// Round 3
// baseline (639.779 us; speedup 1.0000x reference)
//
#include <hip/hip_runtime.h>
#include <hip/hip_bf16.h>

typedef unsigned short u16;
typedef __attribute__((ext_vector_type(8))) short short8;   // bf16x8 MFMA frag (4 VGPR)
typedef __attribute__((ext_vector_type(4))) float float4v;  // fp32x4 acc
typedef __attribute__((ext_vector_type(4))) unsigned int uint4v; // 16B vector

__device__ __forceinline__ u16 f2bf(float f) {
    union { float f; unsigned int u; } v; v.f = f;
    unsigned int r = v.u + 0x7fffu + ((v.u >> 16) & 1u);  // RNE
    return (u16)(r >> 16);
}
__device__ __forceinline__ float bf2f(u16 h) {
    union { unsigned int u; float f; } v; v.u = ((unsigned int)h) << 16;
    return v.f;
}

// ---------------------------------------------------------------------------
// x: fp32 [8192*1024] -> bf16. 8 elements/thread.
// ---------------------------------------------------------------------------
__global__ __launch_bounds__(256) void convert_x(
    const float* __restrict__ x, u16* __restrict__ xb) {
    int i = (blockIdx.x * 256 + threadIdx.x) * 8;
    float4v a = *(const float4v*)&x[i];
    float4v b = *(const float4v*)&x[i + 4];
    u16 tmp[8] __attribute__((aligned(16)));
#pragma unroll
    for (int j = 0; j < 4; ++j) { tmp[j] = f2bf(a[j]); tmp[4 + j] = f2bf(b[j]); }
    *(uint4v*)&xb[i] = *(uint4v*)tmp;
}

// ---------------------------------------------------------------------------
// Weight transpose+convert: W fp32 [1024][1024] (K x N) -> Wt bf16 (N x K).
// ---------------------------------------------------------------------------
__global__ __launch_bounds__(256) void transpose_w(
    const float* __restrict__ w0, const float* __restrict__ w1,
    const float* __restrict__ w2, const float* __restrict__ w3,
    u16* __restrict__ o0, u16* __restrict__ o1,
    u16* __restrict__ o2, u16* __restrict__ o3) {
    __shared__ u16 t[32][33];
    int z = blockIdx.z;
    const float* w = (z == 0) ? w0 : (z == 1) ? w1 : (z == 2) ? w2 : w3;
    u16* o         = (z == 0) ? o0 : (z == 1) ? o1 : (z == 2) ? o2 : o3;
    int bx = blockIdx.x * 32;   // input col (n)
    int by = blockIdx.y * 32;   // input row (k)
    int x = threadIdx.x, y = threadIdx.y;   // block (32,8)
#pragma unroll
    for (int i = 0; i < 4; ++i)
        t[y + i * 8][x] = f2bf(w[(size_t)(by + y + i * 8) * 1024 + bx + x]);
    __syncthreads();
#pragma unroll
    for (int i = 0; i < 4; ++i)
        o[(size_t)(bx + y + i * 8) * 1024 + by + x] = t[x][y + i * 8];
}

// ---------------------------------------------------------------------------
// GEMM: C[M][N] = A[M][K] @ Bt[N][K]^T, bf16 in, fp32 accum.
// 128x128 tile, BK=32, 256 thr = 4 waves (2x2).
// mode 0: bf16 store [M][N]
// mode 1: bf16 store transposed-per-batch: vt[(b*1024+col)*2048 + (t&2047)]
// mode 2: fp32 store [M][N] (final output)
// ---------------------------------------------------------------------------
__global__ __launch_bounds__(256) void gemm_bt(
    const u16* __restrict__ A, const u16* __restrict__ Bt,
    void* __restrict__ Cout, int M, int N, int K, int mode) {
    __shared__ __attribute__((aligned(16))) u16 As[128 * 40];
    __shared__ __attribute__((aligned(16))) u16 Bs[128 * 40];
    const int tid = threadIdx.x;
    const int m0 = blockIdx.y * 128;
    const int n0 = blockIdx.x * 128;
    const int wid = tid >> 6;
    const int lane = tid & 63;
    const int ln = lane & 15, kq = lane >> 4;
    const int wm = (wid >> 1) * 64, wn = (wid & 1) * 64;

    float4v acc[4][4] = {};
    for (int k0 = 0; k0 < K; k0 += 32) {
#pragma unroll
        for (int i = 0; i < 2; ++i) {
            int idx = tid + i * 256;          // 0..511
            int row = idx >> 2, cg = idx & 3;
            *(uint4v*)&As[row * 40 + cg * 8] =
                *(const uint4v*)&A[(size_t)(m0 + row) * K + k0 + cg * 8];
            *(uint4v*)&Bs[row * 40 + cg * 8] =
                *(const uint4v*)&Bt[(size_t)(n0 + row) * K + k0 + cg * 8];
        }
        __syncthreads();
        short8 af[4], bfr[4];
#pragma unroll
        for (int mt = 0; mt < 4; ++mt)
            af[mt] = *(const short8*)&As[(wm + mt * 16 + ln) * 40 + kq * 8];
#pragma unroll
        for (int nt = 0; nt < 4; ++nt)
            bfr[nt] = *(const short8*)&Bs[(wn + nt * 16 + ln) * 40 + kq * 8];
#pragma unroll
        for (int mt = 0; mt < 4; ++mt)
#pragma unroll
            for (int nt = 0; nt < 4; ++nt)
                acc[mt][nt] = __builtin_amdgcn_mfma_f32_16x16x32_bf16(
                    af[mt], bfr[nt], acc[mt][nt], 0, 0, 0);
        __syncthreads();
    }
    if (mode == 0) {
        u16* C = (u16*)Cout;
#pragma unroll
        for (int mt = 0; mt < 4; ++mt)
#pragma unroll
            for (int nt = 0; nt < 4; ++nt)
#pragma unroll
                for (int r = 0; r < 4; ++r) {
                    int row = m0 + wm + mt * 16 + kq * 4 + r;
                    int col = n0 + wn + nt * 16 + ln;
                    C[(size_t)row * N + col] = f2bf(acc[mt][nt][r]);
                }
    } else if (mode == 1) {
        // V projection: t = token row; write vt[(b*1024 + feat)*2048 + n]
        u16* C = (u16*)Cout;
#pragma unroll
        for (int mt = 0; mt < 4; ++mt)
#pragma unroll
            for (int nt = 0; nt < 4; ++nt)
#pragma unroll
                for (int r = 0; r < 4; ++r) {
                    int t = m0 + wm + mt * 16 + kq * 4 + r;
                    int col = n0 + wn + nt * 16 + ln;
                    int b = t >> 11, n = t & 2047;
                    C[((size_t)(b * 1024 + col)) * 2048 + n] = f2bf(acc[mt][nt][r]);
                }
    } else {
        float* C = (float*)Cout;
#pragma unroll
        for (int mt = 0; mt < 4; ++mt)
#pragma unroll
            for (int nt = 0; nt < 4; ++nt)
#pragma unroll
                for (int r = 0; r < 4; ++r) {
                    int row = m0 + wm + mt * 16 + kq * 4 + r;
                    int col = n0 + wn + nt * 16 + ln;
                    C[(size_t)row * N + col] = acc[mt][nt][r];
                }
    }
}

// ---------------------------------------------------------------------------
// Fused attention with head-axis softmax.  LDS 45.5 KB static.
// wg = (b, q-tile of 32). 512 thr = 8 waves, 2 heads/wave. Q in registers.
// Per k-tile (32 keys): S = Q@K^T (K frags gathered from global) -> E=exp(S)
// in LDS -> Dinv = 1/sum_h E -> ctx += (E*Dinv) @ V (V frags from global vt).
// qb and cb alias (ctx overwrites q_buf) — each block reads its own Q rows
// into registers before the loop and writes only those rows at the end.
// ---------------------------------------------------------------------------
__global__ __launch_bounds__(512) void attn_kernel(
    const u16* qb, const u16* __restrict__ kb,
    const u16* __restrict__ vt, u16* cb) {
    __shared__ __attribute__((aligned(16))) u16 E[16 * 32 * 40];   // [h][q][k] 40960 B
    __shared__ float Di[32 * 36];                                   // [q][k] 4608 B

    const int b = blockIdx.y;
    const int q0 = blockIdx.x * 32;
    const int tid = threadIdx.x;
    const int wid = tid >> 6, lane = tid & 63;
    const int ln = lane & 15, kq = lane >> 4;

    // Preload Q fragments: heads h = wid*2 + hh
    short8 aq[2][2][2];   // [hh][mt][kc]
#pragma unroll
    for (int hh = 0; hh < 2; ++hh) {
        int h = wid * 2 + hh;
#pragma unroll
        for (int mt = 0; mt < 2; ++mt)
#pragma unroll
            for (int kc = 0; kc < 2; ++kc)
                aq[hh][mt][kc] = *(const short8*)&qb[
                    (size_t)(b * 2048 + q0 + mt * 16 + ln) * 1024 +
                    h * 64 + kc * 32 + kq * 8];
    }
    float4v cacc[2][2][4] = {};   // [hh][mt][nt]  ctx accumulators

    for (int kt = 0; kt < 2048; kt += 32) {
        // Phase B: S = Q @ K^T (per head), K b-frags gathered from global
        float4v sacc[2][2][2] = {};   // [hh][mt][nt]
#pragma unroll
        for (int hh = 0; hh < 2; ++hh) {
            int h = wid * 2 + hh;
#pragma unroll
            for (int kc = 0; kc < 2; ++kc) {
                short8 bk[2];
#pragma unroll
                for (int nt = 0; nt < 2; ++nt)
                    bk[nt] = *(const short8*)&kb[
                        (size_t)(b * 2048 + kt + nt * 16 + ln) * 1024 +
                        h * 64 + kc * 32 + kq * 8];
#pragma unroll
                for (int mt = 0; mt < 2; ++mt)
#pragma unroll
                    for (int nt = 0; nt < 2; ++nt)
                        sacc[hh][mt][nt] = __builtin_amdgcn_mfma_f32_16x16x32_bf16(
                            aq[hh][mt][kc], bk[nt], sacc[hh][mt][nt], 0, 0, 0);
            }
        }
        __syncthreads();   // previous Phase D done reading E
#pragma unroll
        for (int hh = 0; hh < 2; ++hh) {
            int h = wid * 2 + hh;
#pragma unroll
            for (int mt = 0; mt < 2; ++mt)
#pragma unroll
                for (int nt = 0; nt < 2; ++nt)
#pragma unroll
                    for (int r = 0; r < 4; ++r) {
                        float s = sacc[hh][mt][nt][r] * 0.125f;
                        s = fminf(s, 80.0f);
                        float e = __expf(s);
                        E[(h * 32 + mt * 16 + kq * 4 + r) * 40 + nt * 16 + ln] = f2bf(e);
                    }
        }
        __syncthreads();

        // Phase C: Dinv = 1 / sum_h E
#pragma unroll
        for (int i = 0; i < 2; ++i) {
            int p = tid + i * 512;            // 0..1023
            int q = p >> 5, kk = p & 31;
            float d = 0.f;
#pragma unroll
            for (int h = 0; h < 16; ++h)
                d += bf2f(E[(h * 32 + q) * 40 + kk]);
            Di[q * 36 + kk] = 1.0f / d;
        }
        __syncthreads();

        // Phase D: ctx += (E * Dinv) @ V, V b-frags gathered from global vt
#pragma unroll
        for (int hh = 0; hh < 2; ++hh) {
            int h = wid * 2 + hh;
            short8 ap[2];
#pragma unroll
            for (int mt = 0; mt < 2; ++mt) {
                const u16* ep = &E[(h * 32 + mt * 16 + ln) * 40 + kq * 8];
                const float* dp = &Di[(mt * 16 + ln) * 36 + kq * 8];
                u16 tmp[8] __attribute__((aligned(16)));
#pragma unroll
                for (int j = 0; j < 8; ++j)
                    tmp[j] = f2bf(bf2f(ep[j]) * dp[j]);
                ap[mt] = *(short8*)tmp;
            }
#pragma unroll
            for (int nt = 0; nt < 4; ++nt) {
                short8 bv = *(const short8*)&vt[
                    (size_t)(b * 1024 + h * 64 + nt * 16 + ln) * 2048 + kt + kq * 8];
#pragma unroll
                for (int mt = 0; mt < 2; ++mt)
                    cacc[hh][mt][nt] = __builtin_amdgcn_mfma_f32_16x16x32_bf16(
                        ap[mt], bv, cacc[hh][mt][nt], 0, 0, 0);
            }
        }
        // barrier before next E write is the one after next Phase B's MFMAs
    }

    // Epilogue: ctx[b*2048+q][h*64+d], bf16  (cb aliases qb — same rows only)
#pragma unroll
    for (int hh = 0; hh < 2; ++hh) {
        int h = wid * 2 + hh;
#pragma unroll
        for (int mt = 0; mt < 2; ++mt)
#pragma unroll
            for (int nt = 0; nt < 4; ++nt)
#pragma unroll
                for (int r = 0; r < 4; ++r) {
                    int row = b * 2048 + q0 + mt * 16 + kq * 4 + r;
                    int col = h * 64 + nt * 16 + ln;
                    cb[(size_t)row * 1024 + col] = f2bf(cacc[hh][mt][nt][r]);
                }
    }
}

// ---------------------------------------------------------------------------
extern "C" void kernel_launch(void* const* d_in, const int* in_sizes, int n_in,
                              void* d_out, int out_size, void* d_ws, size_t ws_size,
                              hipStream_t stream) {
    const float* x   = (const float*)d_in[0];   // [8192][1024] fp32
    const float* w_q = (const float*)d_in[1];   // [1024][1024] fp32 (K x N)
    const float* w_k = (const float*)d_in[2];
    const float* w_v = (const float*)d_in[3];
    const float* w_o = (const float*)d_in[4];

    char* ws = (char*)d_ws;
    const size_t SZ_W   = (size_t)1024 * 1024 * 2;   // 2 MiB
    const size_t SZ_TOK = (size_t)8192 * 1024 * 2;   // 16 MiB
    // ws layout (40 MiB): x_bf | wtq wtk wtv wto | q_buf(=ctx)
    u16* x_bf  = (u16*)(ws);
    u16* wtq   = (u16*)(ws + SZ_TOK);
    u16* wtk   = (u16*)(ws + SZ_TOK + SZ_W);
    u16* wtv   = (u16*)(ws + SZ_TOK + 2 * SZ_W);
    u16* wto   = (u16*)(ws + SZ_TOK + 3 * SZ_W);
    u16* q_buf = (u16*)(ws + SZ_TOK + 4 * SZ_W);     // also ctx (aliased)
    // k_buf / vt_buf live in d_out (32 MiB fp32) — dead before final GEMM writes it
    u16* k_buf  = (u16*)d_out;
    u16* vt_buf = (u16*)d_out + (size_t)8192 * 1024;

    // 0. convert x to bf16
    convert_x<<<4096, 256, 0, stream>>>(x, x_bf);

    // 1. transpose+convert weights to Bt (N x K) bf16 layout
    transpose_w<<<dim3(32, 32, 4), dim3(32, 8), 0, stream>>>(
        w_q, w_k, w_v, w_o, wtq, wtk, wtv, wto);

    // 2. QKV projections (V written directly in transposed [b*1024+f][2048] layout)
    gemm_bt<<<dim3(8, 64), 256, 0, stream>>>(x_bf, wtq, q_buf, 8192, 1024, 1024, 0);
    gemm_bt<<<dim3(8, 64), 256, 0, stream>>>(x_bf, wtk, k_buf, 8192, 1024, 1024, 0);
    gemm_bt<<<dim3(8, 64), 256, 0, stream>>>(x_bf, wtv, vt_buf, 8192, 1024, 1024, 1);

    // 3. fused attention with head-axis softmax (ctx written into q_buf)
    attn_kernel<<<dim3(64, 4), 512, 0, stream>>>(q_buf, k_buf, vt_buf, q_buf);

    // 4. output projection -> fp32 d_out (overwrites k_buf/vt_buf scratch)
    gemm_bt<<<dim3(8, 64), 256, 0, stream>>>(q_buf, wto, d_out, 8192, 1024, 1024, 2);
}

// Round 4
// 516.559 us; speedup vs baseline: 1.2385x; 1.2385x over previous
//
#include <hip/hip_runtime.h>
#include <hip/hip_bf16.h>

typedef unsigned short u16;
typedef unsigned int u32;
typedef __attribute__((ext_vector_type(8))) short short8;   // bf16x8 MFMA frag (4 VGPR)
typedef __attribute__((ext_vector_type(4))) float float4v;  // fp32x4 acc
typedef __attribute__((ext_vector_type(4))) unsigned int uint4v; // 16B vector

__device__ __forceinline__ u16 f2bf(float f) {
    union { float f; unsigned int u; } v; v.f = f;
    unsigned int r = v.u + 0x7fffu + ((v.u >> 16) & 1u);  // RNE
    return (u16)(r >> 16);
}

// async 16B global -> LDS (lane i lands at ldsbase + i*16)
__device__ __forceinline__ void gld_lds16(const u16* g, u16* l) {
    __builtin_amdgcn_global_load_lds(
        (const __attribute__((address_space(1))) u32*)g,
        (__attribute__((address_space(3))) u32*)l, 16, 0, 0);
}

// ---------------------------------------------------------------------------
// x: fp32 [8192*1024] -> bf16. 8 elements/thread.
// ---------------------------------------------------------------------------
__global__ __launch_bounds__(256) void convert_x(
    const float* __restrict__ x, u16* __restrict__ xb) {
    int i = (blockIdx.x * 256 + threadIdx.x) * 8;
    float4v a = *(const float4v*)&x[i];
    float4v b = *(const float4v*)&x[i + 4];
    u16 tmp[8] __attribute__((aligned(16)));
#pragma unroll
    for (int j = 0; j < 4; ++j) { tmp[j] = f2bf(a[j]); tmp[4 + j] = f2bf(b[j]); }
    *(uint4v*)&xb[i] = *(uint4v*)tmp;
}

// ---------------------------------------------------------------------------
// Weight transpose+convert: W fp32 [1024][1024] (K x N) -> Wt bf16 (N x K).
// ---------------------------------------------------------------------------
__global__ __launch_bounds__(256) void transpose_w(
    const float* __restrict__ w0, const float* __restrict__ w1,
    const float* __restrict__ w2, const float* __restrict__ w3,
    u16* __restrict__ o0, u16* __restrict__ o1,
    u16* __restrict__ o2, u16* __restrict__ o3) {
    __shared__ u16 t[32][33];
    int z = blockIdx.z;
    const float* w = (z == 0) ? w0 : (z == 1) ? w1 : (z == 2) ? w2 : w3;
    u16* o         = (z == 0) ? o0 : (z == 1) ? o1 : (z == 2) ? o2 : o3;
    int bx = blockIdx.x * 32;   // input col (n)
    int by = blockIdx.y * 32;   // input row (k)
    int x = threadIdx.x, y = threadIdx.y;   // block (32,8)
#pragma unroll
    for (int i = 0; i < 4; ++i)
        t[y + i * 8][x] = f2bf(w[(size_t)(by + y + i * 8) * 1024 + bx + x]);
    __syncthreads();
#pragma unroll
    for (int i = 0; i < 4; ++i)
        o[(size_t)(bx + y + i * 8) * 1024 + by + x] = t[x][y + i * 8];
}

// ---------------------------------------------------------------------------
// GEMM: C[M][N] = A[M][K] @ Bt[N][K]^T, bf16 in, fp32 accum.
// 128x128 tile, BK=32, 256 thr = 4 waves (2x2). m97-style: global_load_lds
// width-16 staging into UNPADDED [128][32] LDS (2-way bank alias only = free).
// mode 0: bf16 [M][N]; mode 1: bf16 vt[(b*1024+col)*2048+(t&2047)]; mode 2: fp32 [M][N]
// ---------------------------------------------------------------------------
__global__ __launch_bounds__(256) void gemm_bt(
    const u16* __restrict__ A, const u16* __restrict__ Bt,
    void* __restrict__ Cout, int M, int N, int K, int mode) {
    __shared__ __attribute__((aligned(16))) u16 As[128 * 32];
    __shared__ __attribute__((aligned(16))) u16 Bs[128 * 32];
    const int tid = threadIdx.x;
    const int m0 = blockIdx.y * 128;
    const int n0 = blockIdx.x * 128;
    const int wid = tid >> 6;
    const int lane = tid & 63;
    const int ln = lane & 15, kq = lane >> 4;
    const int wm = (wid >> 1) * 64, wn = (wid & 1) * 64;

    float4v acc[4][4] = {};
    for (int k0 = 0; k0 < K; k0 += 32) {
#pragma unroll
        for (int i = 0; i < 2; ++i) {
            int chunk = tid + i * 256;          // 16B chunk id, 0..511
            int row = chunk >> 2, cg = chunk & 3;
            // wave-uniform LDS base: chunks [i*256 + wid*64 , +64)
            u16* lA = &As[(size_t)(i * 256 + wid * 64) * 8];
            u16* lB = &Bs[(size_t)(i * 256 + wid * 64) * 8];
            gld_lds16(&A[(size_t)(m0 + row) * K + k0 + cg * 8], lA);
            gld_lds16(&Bt[(size_t)(n0 + row) * K + k0 + cg * 8], lB);
        }
        __syncthreads();
        short8 af[4], bfr[4];
#pragma unroll
        for (int mt = 0; mt < 4; ++mt)
            af[mt] = *(const short8*)&As[(wm + mt * 16 + ln) * 32 + kq * 8];
#pragma unroll
        for (int nt = 0; nt < 4; ++nt)
            bfr[nt] = *(const short8*)&Bs[(wn + nt * 16 + ln) * 32 + kq * 8];
#pragma unroll
        for (int mt = 0; mt < 4; ++mt)
#pragma unroll
            for (int nt = 0; nt < 4; ++nt)
                acc[mt][nt] = __builtin_amdgcn_mfma_f32_16x16x32_bf16(
                    af[mt], bfr[nt], acc[mt][nt], 0, 0, 0);
        __syncthreads();
    }
    if (mode == 0) {
        u16* C = (u16*)Cout;
#pragma unroll
        for (int mt = 0; mt < 4; ++mt)
#pragma unroll
            for (int nt = 0; nt < 4; ++nt)
#pragma unroll
                for (int r = 0; r < 4; ++r) {
                    int row = m0 + wm + mt * 16 + kq * 4 + r;
                    int col = n0 + wn + nt * 16 + ln;
                    C[(size_t)row * N + col] = f2bf(acc[mt][nt][r]);
                }
    } else if (mode == 1) {
        u16* C = (u16*)Cout;
#pragma unroll
        for (int mt = 0; mt < 4; ++mt)
#pragma unroll
            for (int nt = 0; nt < 4; ++nt)
#pragma unroll
                for (int r = 0; r < 4; ++r) {
                    int t = m0 + wm + mt * 16 + kq * 4 + r;
                    int col = n0 + wn + nt * 16 + ln;
                    int b = t >> 11, n = t & 2047;
                    C[((size_t)(b * 1024 + col)) * 2048 + n] = f2bf(acc[mt][nt][r]);
                }
    } else {
        float* C = (float*)Cout;
#pragma unroll
        for (int mt = 0; mt < 4; ++mt)
#pragma unroll
            for (int nt = 0; nt < 4; ++nt)
#pragma unroll
                for (int r = 0; r < 4; ++r) {
                    int row = m0 + wm + mt * 16 + kq * 4 + r;
                    int col = n0 + wn + nt * 16 + ln;
                    C[(size_t)row * N + col] = acc[mt][nt][r];
                }
    }
}

// ---------------------------------------------------------------------------
// Fused attention, head-axis softmax.  E now fp32 in LDS (78.3 KB total).
// All 16 K/V global gathers hoisted+batched at iteration top: one latency
// exposure for K (first use = Phase B MFMA), V fully hidden (used 3 barriers
// later in Phase D).  qb/cb alias — block reads own Q rows before writing.
// ---------------------------------------------------------------------------
__global__ __launch_bounds__(512, 2) void attn_kernel(
    const u16* qb, const u16* __restrict__ kb,
    const u16* __restrict__ vt, u16* cb) {
    __shared__ float E[16 * 32 * 36];   // [h][q][k+pad] 73728 B
    __shared__ float Di[32 * 36];       // [q][k+pad]     4608 B

    const int b = blockIdx.y;
    const int q0 = blockIdx.x * 32;
    const int tid = threadIdx.x;
    const int wid = tid >> 6, lane = tid & 63;
    const int ln = lane & 15, kq = lane >> 4;

    // Preload Q fragments: heads h = wid*2 + hh
    short8 aq[2][2][2];   // [hh][mt][kc]
#pragma unroll
    for (int hh = 0; hh < 2; ++hh) {
        int h = wid * 2 + hh;
#pragma unroll
        for (int mt = 0; mt < 2; ++mt)
#pragma unroll
            for (int kc = 0; kc < 2; ++kc)
                aq[hh][mt][kc] = *(const short8*)&qb[
                    (size_t)(b * 2048 + q0 + mt * 16 + ln) * 1024 +
                    h * 64 + kc * 32 + kq * 8];
    }
    float4v cacc[2][2][4] = {};   // [hh][mt][nt]  ctx accumulators

#pragma unroll 1
    for (int kt = 0; kt < 2048; kt += 32) {
        // ---- hoisted batched gathers: K first (used now), V second (used late)
        short8 bk[2][2][2];   // [hh][kc][nt]
        short8 bv[2][4];      // [hh][nt]
#pragma unroll
        for (int hh = 0; hh < 2; ++hh) {
            int h = wid * 2 + hh;
#pragma unroll
            for (int kc = 0; kc < 2; ++kc)
#pragma unroll
                for (int nt = 0; nt < 2; ++nt)
                    bk[hh][kc][nt] = *(const short8*)&kb[
                        (size_t)(b * 2048 + kt + nt * 16 + ln) * 1024 +
                        h * 64 + kc * 32 + kq * 8];
        }
#pragma unroll
        for (int hh = 0; hh < 2; ++hh) {
            int h = wid * 2 + hh;
#pragma unroll
            for (int nt = 0; nt < 4; ++nt)
                bv[hh][nt] = *(const short8*)&vt[
                    (size_t)(b * 1024 + h * 64 + nt * 16 + ln) * 2048 + kt + kq * 8];
        }

        // ---- Phase B: S = Q @ K^T
        float4v sacc[2][2][2] = {};   // [hh][mt][nt]
#pragma unroll
        for (int hh = 0; hh < 2; ++hh)
#pragma unroll
            for (int kc = 0; kc < 2; ++kc)
#pragma unroll
                for (int mt = 0; mt < 2; ++mt)
#pragma unroll
                    for (int nt = 0; nt < 2; ++nt)
                        sacc[hh][mt][nt] = __builtin_amdgcn_mfma_f32_16x16x32_bf16(
                            aq[hh][mt][kc], bk[hh][kc][nt], sacc[hh][mt][nt], 0, 0, 0);
        __syncthreads();   // previous Phase D done reading E
#pragma unroll
        for (int hh = 0; hh < 2; ++hh) {
            int h = wid * 2 + hh;
#pragma unroll
            for (int mt = 0; mt < 2; ++mt)
#pragma unroll
                for (int nt = 0; nt < 2; ++nt)
#pragma unroll
                    for (int r = 0; r < 4; ++r) {
                        float s = sacc[hh][mt][nt][r] * 0.125f;
                        E[(h * 32 + mt * 16 + kq * 4 + r) * 36 + nt * 16 + ln] =
                            __expf(fminf(s, 80.0f));
                    }
        }
        __syncthreads();

        // ---- Phase C: Dinv = 1 / sum_h E   (16 independent ds_reads, batched)
#pragma unroll
        for (int i = 0; i < 2; ++i) {
            int p = tid + i * 512;            // 0..1023
            int q = p >> 5, kk = p & 31;
            float d = 0.f;
#pragma unroll
            for (int h = 0; h < 16; ++h)
                d += E[(h * 32 + q) * 36 + kk];
            Di[q * 36 + kk] = __builtin_amdgcn_rcpf(d);
        }
        __syncthreads();

        // ---- Phase D: ctx += (E * Dinv) @ V
#pragma unroll
        for (int hh = 0; hh < 2; ++hh) {
            int h = wid * 2 + hh;
            short8 ap[2];
#pragma unroll
            for (int mt = 0; mt < 2; ++mt) {
                const float* ep = &E[(h * 32 + mt * 16 + ln) * 36 + kq * 8];
                const float* dp = &Di[(mt * 16 + ln) * 36 + kq * 8];
                u16 tmp[8] __attribute__((aligned(16)));
#pragma unroll
                for (int j = 0; j < 8; ++j)
                    tmp[j] = f2bf(ep[j] * dp[j]);
                ap[mt] = *(short8*)tmp;
            }
#pragma unroll
            for (int nt = 0; nt < 4; ++nt)
#pragma unroll
                for (int mt = 0; mt < 2; ++mt)
                    cacc[hh][mt][nt] = __builtin_amdgcn_mfma_f32_16x16x32_bf16(
                        ap[mt], bv[hh][nt], cacc[hh][mt][nt], 0, 0, 0);
        }
        // barrier before next E write is the one after next Phase B's MFMAs
    }

    // Epilogue: ctx[b*2048+q][h*64+d], bf16  (cb aliases qb — same rows only)
#pragma unroll
    for (int hh = 0; hh < 2; ++hh) {
        int h = wid * 2 + hh;
#pragma unroll
        for (int mt = 0; mt < 2; ++mt)
#pragma unroll
            for (int nt = 0; nt < 4; ++nt)
#pragma unroll
                for (int r = 0; r < 4; ++r) {
                    int row = b * 2048 + q0 + mt * 16 + kq * 4 + r;
                    int col = h * 64 + nt * 16 + ln;
                    cb[(size_t)row * 1024 + col] = f2bf(cacc[hh][mt][nt][r]);
                }
    }
}

// ---------------------------------------------------------------------------
extern "C" void kernel_launch(void* const* d_in, const int* in_sizes, int n_in,
                              void* d_out, int out_size, void* d_ws, size_t ws_size,
                              hipStream_t stream) {
    const float* x   = (const float*)d_in[0];   // [8192][1024] fp32
    const float* w_q = (const float*)d_in[1];   // [1024][1024] fp32 (K x N)
    const float* w_k = (const float*)d_in[2];
    const float* w_v = (const float*)d_in[3];
    const float* w_o = (const float*)d_in[4];

    char* ws = (char*)d_ws;
    const size_t SZ_W   = (size_t)1024 * 1024 * 2;   // 2 MiB
    const size_t SZ_TOK = (size_t)8192 * 1024 * 2;   // 16 MiB
    // ws layout (40 MiB): x_bf | wtq wtk wtv wto | q_buf(=ctx)
    u16* x_bf  = (u16*)(ws);
    u16* wtq   = (u16*)(ws + SZ_TOK);
    u16* wtk   = (u16*)(ws + SZ_TOK + SZ_W);
    u16* wtv   = (u16*)(ws + SZ_TOK + 2 * SZ_W);
    u16* wto   = (u16*)(ws + SZ_TOK + 3 * SZ_W);
    u16* q_buf = (u16*)(ws + SZ_TOK + 4 * SZ_W);     // also ctx (aliased)
    // k_buf / vt_buf live in d_out (32 MiB fp32) — dead before final GEMM writes it
    u16* k_buf  = (u16*)d_out;
    u16* vt_buf = (u16*)d_out + (size_t)8192 * 1024;

    // 0. convert x to bf16
    convert_x<<<4096, 256, 0, stream>>>(x, x_bf);

    // 1. transpose+convert weights to Bt (N x K) bf16 layout
    transpose_w<<<dim3(32, 32, 4), dim3(32, 8), 0, stream>>>(
        w_q, w_k, w_v, w_o, wtq, wtk, wtv, wto);

    // 2. QKV projections (V written directly in transposed [b*1024+f][2048] layout)
    gemm_bt<<<dim3(8, 64), 256, 0, stream>>>(x_bf, wtq, q_buf, 8192, 1024, 1024, 0);
    gemm_bt<<<dim3(8, 64), 256, 0, stream>>>(x_bf, wtk, k_buf, 8192, 1024, 1024, 0);
    gemm_bt<<<dim3(8, 64), 256, 0, stream>>>(x_bf, wtv, vt_buf, 8192, 1024, 1024, 1);

    // 3. fused attention with head-axis softmax (ctx written into q_buf)
    attn_kernel<<<dim3(64, 4), 512, 0, stream>>>(q_buf, k_buf, vt_buf, q_buf);

    // 4. output projection -> fp32 d_out (overwrites k_buf/vt_buf scratch)
    gemm_bt<<<dim3(8, 64), 256, 0, stream>>>(q_buf, wto, d_out, 8192, 1024, 1024, 2);
}

// Round 5
// 509.237 us; speedup vs baseline: 1.2563x; 1.0144x over previous
//
#include <hip/hip_runtime.h>
#include <hip/hip_bf16.h>

typedef unsigned short u16;
typedef unsigned int u32;
typedef __attribute__((ext_vector_type(8))) short short8;   // bf16x8 MFMA frag (4 VGPR)
typedef __attribute__((ext_vector_type(4))) float float4v;  // fp32x4 acc
typedef __attribute__((ext_vector_type(4))) unsigned int uint4v; // 16B vector

__device__ __forceinline__ u16 f2bf(float f) {
    union { float f; unsigned int u; } v; v.f = f;
    unsigned int r = v.u + 0x7fffu + ((v.u >> 16) & 1u);  // RNE
    return (u16)(r >> 16);
}
__device__ __forceinline__ float bf2f(u16 h) {
    union { unsigned int u; float f; } v; v.u = ((unsigned int)h) << 16;
    return v.f;
}

// async 16B global -> LDS (lane i lands at ldsbase + i*16)
__device__ __forceinline__ void gld_lds16(const u16* g, u16* l) {
    __builtin_amdgcn_global_load_lds(
        (const __attribute__((address_space(1))) u32*)g,
        (__attribute__((address_space(3))) u32*)l, 16, 0, 0);
}

// ---------------------------------------------------------------------------
// x: fp32 [8192*1024] -> bf16. 8 elements/thread.
// ---------------------------------------------------------------------------
__global__ __launch_bounds__(256) void convert_x(
    const float* __restrict__ x, u16* __restrict__ xb) {
    int i = (blockIdx.x * 256 + threadIdx.x) * 8;
    float4v a = *(const float4v*)&x[i];
    float4v b = *(const float4v*)&x[i + 4];
    u16 tmp[8] __attribute__((aligned(16)));
#pragma unroll
    for (int j = 0; j < 4; ++j) { tmp[j] = f2bf(a[j]); tmp[4 + j] = f2bf(b[j]); }
    *(uint4v*)&xb[i] = *(uint4v*)tmp;
}

// ---------------------------------------------------------------------------
// Weight transpose+convert: W fp32 [1024][1024] (K x N) -> Wt bf16 (N x K).
// ---------------------------------------------------------------------------
__global__ __launch_bounds__(256) void transpose_w(
    const float* __restrict__ w0, const float* __restrict__ w1,
    const float* __restrict__ w2, const float* __restrict__ w3,
    u16* __restrict__ o0, u16* __restrict__ o1,
    u16* __restrict__ o2, u16* __restrict__ o3) {
    __shared__ u16 t[32][33];
    int z = blockIdx.z;
    const float* w = (z == 0) ? w0 : (z == 1) ? w1 : (z == 2) ? w2 : w3;
    u16* o         = (z == 0) ? o0 : (z == 1) ? o1 : (z == 2) ? o2 : o3;
    int bx = blockIdx.x * 32;   // input col (n)
    int by = blockIdx.y * 32;   // input row (k)
    int x = threadIdx.x, y = threadIdx.y;   // block (32,8)
#pragma unroll
    for (int i = 0; i < 4; ++i)
        t[y + i * 8][x] = f2bf(w[(size_t)(by + y + i * 8) * 1024 + bx + x]);
    __syncthreads();
#pragma unroll
    for (int i = 0; i < 4; ++i)
        o[(size_t)(bx + y + i * 8) * 1024 + by + x] = t[x][y + i * 8];
}

// ---------------------------------------------------------------------------
// GEMM: C[M][N] = A[M][K] @ Bt[N][K]^T, bf16 in, fp32 accum. (unchanged R4)
// ---------------------------------------------------------------------------
__global__ __launch_bounds__(256) void gemm_bt(
    const u16* __restrict__ A, const u16* __restrict__ Bt,
    void* __restrict__ Cout, int M, int N, int K, int mode) {
    __shared__ __attribute__((aligned(16))) u16 As[128 * 32];
    __shared__ __attribute__((aligned(16))) u16 Bs[128 * 32];
    const int tid = threadIdx.x;
    const int m0 = blockIdx.y * 128;
    const int n0 = blockIdx.x * 128;
    const int wid = tid >> 6;
    const int lane = tid & 63;
    const int ln = lane & 15, kq = lane >> 4;
    const int wm = (wid >> 1) * 64, wn = (wid & 1) * 64;

    float4v acc[4][4] = {};
    for (int k0 = 0; k0 < K; k0 += 32) {
#pragma unroll
        for (int i = 0; i < 2; ++i) {
            int chunk = tid + i * 256;          // 16B chunk id, 0..511
            int row = chunk >> 2, cg = chunk & 3;
            u16* lA = &As[(size_t)(i * 256 + wid * 64) * 8];
            u16* lB = &Bs[(size_t)(i * 256 + wid * 64) * 8];
            gld_lds16(&A[(size_t)(m0 + row) * K + k0 + cg * 8], lA);
            gld_lds16(&Bt[(size_t)(n0 + row) * K + k0 + cg * 8], lB);
        }
        __syncthreads();
        short8 af[4], bfr[4];
#pragma unroll
        for (int mt = 0; mt < 4; ++mt)
            af[mt] = *(const short8*)&As[(wm + mt * 16 + ln) * 32 + kq * 8];
#pragma unroll
        for (int nt = 0; nt < 4; ++nt)
            bfr[nt] = *(const short8*)&Bs[(wn + nt * 16 + ln) * 32 + kq * 8];
#pragma unroll
        for (int mt = 0; mt < 4; ++mt)
#pragma unroll
            for (int nt = 0; nt < 4; ++nt)
                acc[mt][nt] = __builtin_amdgcn_mfma_f32_16x16x32_bf16(
                    af[mt], bfr[nt], acc[mt][nt], 0, 0, 0);
        __syncthreads();
    }
    if (mode == 0) {
        u16* C = (u16*)Cout;
#pragma unroll
        for (int mt = 0; mt < 4; ++mt)
#pragma unroll
            for (int nt = 0; nt < 4; ++nt)
#pragma unroll
                for (int r = 0; r < 4; ++r) {
                    int row = m0 + wm + mt * 16 + kq * 4 + r;
                    int col = n0 + wn + nt * 16 + ln;
                    C[(size_t)row * N + col] = f2bf(acc[mt][nt][r]);
                }
    } else if (mode == 1) {
        u16* C = (u16*)Cout;
#pragma unroll
        for (int mt = 0; mt < 4; ++mt)
#pragma unroll
            for (int nt = 0; nt < 4; ++nt)
#pragma unroll
                for (int r = 0; r < 4; ++r) {
                    int t = m0 + wm + mt * 16 + kq * 4 + r;
                    int col = n0 + wn + nt * 16 + ln;
                    int b = t >> 11, n = t & 2047;
                    C[((size_t)(b * 1024 + col)) * 2048 + n] = f2bf(acc[mt][nt][r]);
                }
    } else {
        float* C = (float*)Cout;
#pragma unroll
        for (int mt = 0; mt < 4; ++mt)
#pragma unroll
            for (int nt = 0; nt < 4; ++nt)
#pragma unroll
                for (int r = 0; r < 4; ++r) {
                    int row = m0 + wm + mt * 16 + kq * 4 + r;
                    int col = n0 + wn + nt * 16 + ln;
                    C[(size_t)row * N + col] = acc[mt][nt][r];
                }
    }
}

// ---------------------------------------------------------------------------
// Fused attention, head-axis softmax.  R5: 1024 threads = 16 waves (1 head
// per wave) for 2x wave-level latency hiding; E ping-pong (bf16) cuts
// barriers 3 -> 2 per k-tile.  LDS = 2*40960 (E) + 4608 (Di) = 86.5 KB.
// qb/cb alias — block reads own Q rows before writing same rows.
// ---------------------------------------------------------------------------
__global__ __launch_bounds__(1024) void attn_kernel(
    const u16* qb, const u16* __restrict__ kb,
    const u16* __restrict__ vt, u16* cb) {
    __shared__ __attribute__((aligned(16))) u16 E[2][16 * 32 * 40]; // 81920 B
    __shared__ float Di[32 * 36];                                   //  4608 B

    const int b = blockIdx.y;
    const int q0 = blockIdx.x * 32;
    const int tid = threadIdx.x;
    const int wid = tid >> 6, lane = tid & 63;   // wid 0..15 = head
    const int ln = lane & 15, kq = lane >> 4;
    const int h = wid;

    // Preload Q fragments for this wave's head
    short8 aq[2][2];   // [mt][kc]
#pragma unroll
    for (int mt = 0; mt < 2; ++mt)
#pragma unroll
        for (int kc = 0; kc < 2; ++kc)
            aq[mt][kc] = *(const short8*)&qb[
                (size_t)(b * 2048 + q0 + mt * 16 + ln) * 1024 +
                h * 64 + kc * 32 + kq * 8];

    float4v cacc[2][4] = {};   // [mt][nt] ctx accumulators (16q x 64d)

#pragma unroll 1
    for (int kt = 0; kt < 2048; kt += 32) {
        const int cur = (kt >> 5) & 1;
        // ---- hoisted batched gathers: K (used now), V (used after 2 barriers)
        short8 bk[2][2];   // [kc][nt]
        short8 bv[4];      // [nt] (d-tiles)
#pragma unroll
        for (int kc = 0; kc < 2; ++kc)
#pragma unroll
            for (int nt = 0; nt < 2; ++nt)
                bk[kc][nt] = *(const short8*)&kb[
                    (size_t)(b * 2048 + kt + nt * 16 + ln) * 1024 +
                    h * 64 + kc * 32 + kq * 8];
#pragma unroll
        for (int nt = 0; nt < 4; ++nt)
            bv[nt] = *(const short8*)&vt[
                (size_t)(b * 1024 + h * 64 + nt * 16 + ln) * 2048 + kt + kq * 8];

        // ---- S = Q @ K^T for this head
        float4v sacc[2][2] = {};   // [mt][nt]
#pragma unroll
        for (int kc = 0; kc < 2; ++kc)
#pragma unroll
            for (int mt = 0; mt < 2; ++mt)
#pragma unroll
                for (int nt = 0; nt < 2; ++nt)
                    sacc[mt][nt] = __builtin_amdgcn_mfma_f32_16x16x32_bf16(
                        aq[mt][kc], bk[kc][nt], sacc[mt][nt], 0, 0, 0);

        // ---- E = exp(S*scale) -> ping-pong buffer (no barrier needed: buffer
        // cur was last read in Phase D two iterations ago, past 2 barriers)
#pragma unroll
        for (int mt = 0; mt < 2; ++mt)
#pragma unroll
            for (int nt = 0; nt < 2; ++nt)
#pragma unroll
                for (int r = 0; r < 4; ++r) {
                    // exp(s*0.125) = exp2(s * 0.125*log2(e))
                    float s = sacc[mt][nt][r] * 0.18033688f;
                    E[cur][(h * 32 + mt * 16 + kq * 4 + r) * 40 + nt * 16 + ln] =
                        f2bf(exp2f(fminf(s, 115.0f)));
                }
        __syncthreads();   // BAR-A: E[cur] complete

        // ---- Dinv = 1 / sum_h E  (1024 threads, one (q,k) each)
        {
            int q = tid >> 5, kk = tid & 31;
            float d = 0.f;
#pragma unroll
            for (int hh = 0; hh < 16; ++hh)
                d += bf2f(E[cur][(hh * 32 + q) * 40 + kk]);
            Di[q * 36 + kk] = __builtin_amdgcn_rcpf(d);
        }
        __syncthreads();   // BAR-B: Di complete

        // ---- ctx += (E * Dinv) @ V
        short8 ap[2];
#pragma unroll
        for (int mt = 0; mt < 2; ++mt) {
            const u16* ep = &E[cur][(h * 32 + mt * 16 + ln) * 40 + kq * 8];
            const float* dp = &Di[(mt * 16 + ln) * 36 + kq * 8];
            u16 tmp[8] __attribute__((aligned(16)));
#pragma unroll
            for (int j = 0; j < 8; ++j)
                tmp[j] = f2bf(bf2f(ep[j]) * dp[j]);
            ap[mt] = *(short8*)tmp;
        }
#pragma unroll
        for (int nt = 0; nt < 4; ++nt)
#pragma unroll
            for (int mt = 0; mt < 2; ++mt)
                cacc[mt][nt] = __builtin_amdgcn_mfma_f32_16x16x32_bf16(
                    ap[mt], bv[nt], cacc[mt][nt], 0, 0, 0);
    }

    // Epilogue: ctx[b*2048+q][h*64+d], bf16  (cb aliases qb — same rows only)
#pragma unroll
    for (int mt = 0; mt < 2; ++mt)
#pragma unroll
        for (int nt = 0; nt < 4; ++nt)
#pragma unroll
            for (int r = 0; r < 4; ++r) {
                int row = b * 2048 + q0 + mt * 16 + kq * 4 + r;
                int col = h * 64 + nt * 16 + ln;
                cb[(size_t)row * 1024 + col] = f2bf(cacc[mt][nt][r]);
            }
}

// ---------------------------------------------------------------------------
extern "C" void kernel_launch(void* const* d_in, const int* in_sizes, int n_in,
                              void* d_out, int out_size, void* d_ws, size_t ws_size,
                              hipStream_t stream) {
    const float* x   = (const float*)d_in[0];   // [8192][1024] fp32
    const float* w_q = (const float*)d_in[1];   // [1024][1024] fp32 (K x N)
    const float* w_k = (const float*)d_in[2];
    const float* w_v = (const float*)d_in[3];
    const float* w_o = (const float*)d_in[4];

    char* ws = (char*)d_ws;
    const size_t SZ_W   = (size_t)1024 * 1024 * 2;   // 2 MiB
    const size_t SZ_TOK = (size_t)8192 * 1024 * 2;   // 16 MiB
    // ws layout (40 MiB): x_bf | wtq wtk wtv wto | q_buf(=ctx)
    u16* x_bf  = (u16*)(ws);
    u16* wtq   = (u16*)(ws + SZ_TOK);
    u16* wtk   = (u16*)(ws + SZ_TOK + SZ_W);
    u16* wtv   = (u16*)(ws + SZ_TOK + 2 * SZ_W);
    u16* wto   = (u16*)(ws + SZ_TOK + 3 * SZ_W);
    u16* q_buf = (u16*)(ws + SZ_TOK + 4 * SZ_W);     // also ctx (aliased)
    // k_buf / vt_buf live in d_out (32 MiB fp32) — dead before final GEMM writes it
    u16* k_buf  = (u16*)d_out;
    u16* vt_buf = (u16*)d_out + (size_t)8192 * 1024;

    // 0. convert x to bf16
    convert_x<<<4096, 256, 0, stream>>>(x, x_bf);

    // 1. transpose+convert weights to Bt (N x K) bf16 layout
    transpose_w<<<dim3(32, 32, 4), dim3(32, 8), 0, stream>>>(
        w_q, w_k, w_v, w_o, wtq, wtk, wtv, wto);

    // 2. QKV projections (V written directly in transposed [b*1024+f][2048] layout)
    gemm_bt<<<dim3(8, 64), 256, 0, stream>>>(x_bf, wtq, q_buf, 8192, 1024, 1024, 0);
    gemm_bt<<<dim3(8, 64), 256, 0, stream>>>(x_bf, wtk, k_buf, 8192, 1024, 1024, 0);
    gemm_bt<<<dim3(8, 64), 256, 0, stream>>>(x_bf, wtv, vt_buf, 8192, 1024, 1024, 1);

    // 3. fused attention with head-axis softmax (ctx written into q_buf)
    attn_kernel<<<dim3(64, 4), 1024, 0, stream>>>(q_buf, k_buf, vt_buf, q_buf);

    // 4. output projection -> fp32 d_out (overwrites k_buf/vt_buf scratch)
    gemm_bt<<<dim3(8, 64), 256, 0, stream>>>(q_buf, wto, d_out, 8192, 1024, 1024, 2);
}